// Round 1
// baseline (9260.934 us; speedup 1.0000x reference)
//
#include <hip/hip_runtime.h>

// GraphSAGE 3-layer inference, fp32 baseline.
// Layer: out = h @ W_self + (segsum(h[src]) * inv_deg) @ W_neigh + b  [+ReLU]
// Fused as [h | agg] (K=512) @ [Ws; Wn], inv_deg folded into A-operand read.

#define NN 100000
#define NE 800000
#define DH 256

__global__ void deg_kernel(const int* __restrict__ dst, float* __restrict__ deg) {
    int e = blockIdx.x * blockDim.x + threadIdx.x;
    if (e < NE) atomicAdd(&deg[dst[e]], 1.0f);
}

__global__ void invdeg_kernel(float* __restrict__ deg) {
    int i = blockIdx.x * blockDim.x + threadIdx.x;
    if (i < NN) deg[i] = 1.0f / fmaxf(deg[i], 1.0f);
}

// One edge per 64-lane group; each lane moves a float4 (64*16B = 1KB = 256 floats).
__global__ __launch_bounds__(256) void agg_kernel(const float* __restrict__ h,
                                                  const int* __restrict__ src,
                                                  const int* __restrict__ dst,
                                                  float* __restrict__ agg) {
    int lane = threadIdx.x & 63;
    int sub  = threadIdx.x >> 6;
    int e = blockIdx.x * 4 + sub;
    if (e >= NE) return;
    int s = src[e], d = dst[e];
    const float4 v = *(const float4*)&h[(size_t)s * DH + lane * 4];
    float* o = &agg[(size_t)d * DH + lane * 4];
    atomicAdd(o + 0, v.x);
    atomicAdd(o + 1, v.y);
    atomicAdd(o + 2, v.z);
    atomicAdd(o + 3, v.w);
}

// C[M,N] = h[M,256] @ Ws[256,N] + (agg[M,256] * invdeg[M]) @ Wn[256,N] + b, opt ReLU.
// 64x64 tile / block, 256 threads, each thread 4x4, BK=16, K total = 512.
__global__ __launch_bounds__(256) void sage_gemm(const float* __restrict__ h,
                                                 const float* __restrict__ agg,
                                                 const float* __restrict__ invdeg,
                                                 const float* __restrict__ Ws,
                                                 const float* __restrict__ Wn,
                                                 const float* __restrict__ bias,
                                                 float* __restrict__ out,
                                                 int M, int N, int relu) {
    __shared__ float As[16][68];  // [k][m], padded row (68*4B = 272B, 16B-divisible)
    __shared__ float Bs[16][68];  // [k][n]

    const int tid = threadIdx.x;
    const int row0 = blockIdx.x * 64;
    const int n0   = blockIdx.y * 64;
    const int tx = tid & 15;   // n group
    const int ty = tid >> 4;   // m group

    const int a_k = tid & 15;
    const int a_m = tid >> 4;   // +0,16,32,48
    const int b_n = tid & 63;
    const int b_k = tid >> 6;   // +0,4,8,12

    float acc[4][4] = {};

    for (int kt = 0; kt < 32; ++kt) {
        const int kg = kt * 16;
        // A tile: rows from h (k<256) or agg*invdeg (k>=256)
        #pragma unroll
        for (int i = 0; i < 4; ++i) {
            int r = row0 + a_m + i * 16;
            int k = kg + a_k;
            float v = 0.f;
            if (r < M) {
                if (k < 256) v = h[(size_t)r * DH + k];
                else         v = agg[(size_t)r * DH + (k - 256)] * invdeg[r];
            }
            As[a_k][a_m + i * 16] = v;
        }
        // B tile: Ws (k<256) or Wn (k>=256)
        #pragma unroll
        for (int i = 0; i < 4; ++i) {
            int k = kg + b_k + i * 4;
            float v = (k < 256) ? Ws[(size_t)k * N + n0 + b_n]
                                : Wn[(size_t)(k - 256) * N + n0 + b_n];
            Bs[b_k + i * 4][b_n] = v;
        }
        __syncthreads();

        #pragma unroll
        for (int k = 0; k < 16; ++k) {
            float4 a4 = *(const float4*)&As[k][ty * 4];
            float4 b4 = *(const float4*)&Bs[k][tx * 4];
            acc[0][0] += a4.x * b4.x; acc[0][1] += a4.x * b4.y; acc[0][2] += a4.x * b4.z; acc[0][3] += a4.x * b4.w;
            acc[1][0] += a4.y * b4.x; acc[1][1] += a4.y * b4.y; acc[1][2] += a4.y * b4.z; acc[1][3] += a4.y * b4.w;
            acc[2][0] += a4.z * b4.x; acc[2][1] += a4.z * b4.y; acc[2][2] += a4.z * b4.z; acc[2][3] += a4.z * b4.w;
            acc[3][0] += a4.w * b4.x; acc[3][1] += a4.w * b4.y; acc[3][2] += a4.w * b4.z; acc[3][3] += a4.w * b4.w;
        }
        __syncthreads();
    }

    #pragma unroll
    for (int i = 0; i < 4; ++i) {
        int r = row0 + ty * 4 + i;
        if (r >= M) continue;
        #pragma unroll
        for (int j = 0; j < 4; ++j) {
            int n = n0 + tx * 4 + j;
            float v = acc[i][j] + bias[n];
            if (relu) v = fmaxf(v, 0.f);
            out[(size_t)r * N + n] = v;
        }
    }
}

extern "C" void kernel_launch(void* const* d_in, const int* in_sizes, int n_in,
                              void* d_out, int out_size, void* d_ws, size_t ws_size,
                              hipStream_t stream) {
    const float* x   = (const float*)d_in[0];
    const int*   src = (const int*)d_in[1];
    const int*   dst = (const int*)d_in[2];
    const float* Ws1 = (const float*)d_in[3];
    const float* Wn1 = (const float*)d_in[4];
    const float* b1  = (const float*)d_in[5];
    const float* Ws2 = (const float*)d_in[6];
    const float* Wn2 = (const float*)d_in[7];
    const float* b2  = (const float*)d_in[8];
    const float* Ws3 = (const float*)d_in[9];
    const float* Wn3 = (const float*)d_in[10];
    const float* b3  = (const float*)d_in[11];

    // workspace layout (floats): deg[131072 pad] | agg[25.6M] | hA[25.6M] | hB[25.6M]
    float* deg = (float*)d_ws;
    float* agg = deg + (1 << 17);
    float* hA  = agg + (size_t)NN * DH;
    float* hB  = hA  + (size_t)NN * DH;

    const size_t aggBytes = (size_t)NN * DH * sizeof(float);

    // degree -> inv_deg (shared by all layers)
    hipMemsetAsync(deg, 0, NN * sizeof(float), stream);
    deg_kernel<<<(NE + 255) / 256, 256, 0, stream>>>(dst, deg);
    invdeg_kernel<<<(NN + 255) / 256, 256, 0, stream>>>(deg);

    const dim3 gemmGrid((NN + 63) / 64, 4);
    const dim3 gemmGrid3((NN + 63) / 64, 1);

    // layer 1
    hipMemsetAsync(agg, 0, aggBytes, stream);
    agg_kernel<<<NE / 4, 256, 0, stream>>>(x, src, dst, agg);
    sage_gemm<<<gemmGrid, 256, 0, stream>>>(x, agg, deg, Ws1, Wn1, b1, hA, NN, 256, 1);

    // layer 2
    hipMemsetAsync(agg, 0, aggBytes, stream);
    agg_kernel<<<NE / 4, 256, 0, stream>>>(hA, src, dst, agg);
    sage_gemm<<<gemmGrid, 256, 0, stream>>>(hA, agg, deg, Ws2, Wn2, b2, hB, NN, 256, 1);

    // layer 3 (no relu, N=64)
    hipMemsetAsync(agg, 0, aggBytes, stream);
    agg_kernel<<<NE / 4, 256, 0, stream>>>(hB, src, dst, agg);
    sage_gemm<<<gemmGrid3, 256, 0, stream>>>(hB, agg, deg, Ws3, Wn3, b3, (float*)d_out, NN, 64, 0);
}

// Round 2
// 1662.592 us; speedup vs baseline: 5.5702x; 5.5702x over previous
//
#include <hip/hip_runtime.h>

// GraphSAGE 3-layer inference, fp32.
// R2: atomic scatter-add replaced by per-launch CSR build + pull-mode gather.
// Layer: out = h @ W_self + mean_agg @ W_neigh + b  [+ReLU]
// GEMM fused as [h | agg] (K=512) @ [Ws; Wn]; agg holds the mean (inv_deg folded).

#define NN 100000
#define NE 800000
#define DH 256

__global__ void degi_kernel(const int* __restrict__ dst, int* __restrict__ deg) {
    int e = blockIdx.x * blockDim.x + threadIdx.x;
    if (e < NE) atomicAdd(&deg[dst[e]], 1);
}

// Single-block exclusive scan of deg -> cursor (start offsets).
// 1024 threads = 16 waves; wave-level shfl scan + LDS combine.
__global__ __launch_bounds__(1024) void scan_kernel(const int* __restrict__ deg,
                                                    int* __restrict__ cursor) {
    __shared__ int wsum[16];
    __shared__ int carry_s;
    const int tid = threadIdx.x, lane = tid & 63, w = tid >> 6;
    if (tid == 0) carry_s = 0;
    __syncthreads();
    for (int base = 0; base < NN; base += 1024) {
        int i = base + tid;
        int v = (i < NN) ? deg[i] : 0;
        // inclusive scan within wave
        int s = v;
        #pragma unroll
        for (int off = 1; off < 64; off <<= 1) {
            int t = __shfl_up(s, off, 64);
            if (lane >= off) s += t;
        }
        if (lane == 63) wsum[w] = s;
        __syncthreads();
        if (w == 0) {
            int ws_ = (lane < 16) ? wsum[lane] : 0;
            int t2 = ws_;
            #pragma unroll
            for (int off = 1; off < 16; off <<= 1) {
                int t = __shfl_up(t2, off, 64);
                if (lane >= off) t2 += t;
            }
            if (lane < 16) wsum[lane] = t2 - ws_;  // exclusive wave prefix
        }
        __syncthreads();
        int excl = carry_s + wsum[w] + (s - v);
        if (i < NN) cursor[i] = excl;
        __syncthreads();
        if (tid == 1023) carry_s = excl + v;  // inclusive of last elem
        __syncthreads();
    }
}

// Bucket src ids by dst. After this, cursor[d] = end offset of node d's bucket.
__global__ void scatter_kernel(const int* __restrict__ src, const int* __restrict__ dst,
                               int* __restrict__ cursor, int* __restrict__ nbr) {
    int e = blockIdx.x * blockDim.x + threadIdx.x;
    if (e < NE) {
        int pos = atomicAdd(&cursor[dst[e]], 1);
        nbr[pos] = src[e];
    }
}

// Pull-mode mean aggregation: one wave per dst node, float4 per lane (256 floats).
__global__ __launch_bounds__(256) void gather_kernel(const float* __restrict__ h,
                                                     const int* __restrict__ nbr,
                                                     const int* __restrict__ cursor,
                                                     const int* __restrict__ deg,
                                                     float* __restrict__ agg) {
    const int lane = threadIdx.x & 63;
    const int sub  = threadIdx.x >> 6;
    const int d = blockIdx.x * 4 + sub;
    if (d >= NN) return;
    const int dg  = deg[d];
    const int end = cursor[d];
    float4 acc = {0.f, 0.f, 0.f, 0.f};
    for (int j = end - dg; j < end; ++j) {
        int s = nbr[j];
        const float4 v = *(const float4*)&h[(size_t)s * DH + lane * 4];
        acc.x += v.x; acc.y += v.y; acc.z += v.z; acc.w += v.w;
    }
    const float inv = 1.0f / fmaxf((float)dg, 1.0f);
    acc.x *= inv; acc.y *= inv; acc.z *= inv; acc.w *= inv;
    *(float4*)&agg[(size_t)d * DH + lane * 4] = acc;
}

// C[M,N] = h[M,256] @ Ws[256,N] + agg[M,256] @ Wn[256,N] + b, opt ReLU.
// 64x64 tile / block, 256 threads, each thread 4x4, BK=16, K total = 512.
__global__ __launch_bounds__(256) void sage_gemm(const float* __restrict__ h,
                                                 const float* __restrict__ agg,
                                                 const float* __restrict__ Ws,
                                                 const float* __restrict__ Wn,
                                                 const float* __restrict__ bias,
                                                 float* __restrict__ out,
                                                 int M, int N, int relu) {
    __shared__ float As[16][68];  // [k][m]
    __shared__ float Bs[16][68];  // [k][n]

    const int tid = threadIdx.x;
    const int row0 = blockIdx.x * 64;
    const int n0   = blockIdx.y * 64;
    const int tx = tid & 15;
    const int ty = tid >> 4;

    const int a_k = tid & 15;
    const int a_m = tid >> 4;
    const int b_n = tid & 63;
    const int b_k = tid >> 6;

    float acc[4][4] = {};

    for (int kt = 0; kt < 32; ++kt) {
        const int kg = kt * 16;
        #pragma unroll
        for (int i = 0; i < 4; ++i) {
            int r = row0 + a_m + i * 16;
            int k = kg + a_k;
            float v = 0.f;
            if (r < M) {
                if (k < 256) v = h[(size_t)r * DH + k];
                else         v = agg[(size_t)r * DH + (k - 256)];
            }
            As[a_k][a_m + i * 16] = v;
        }
        #pragma unroll
        for (int i = 0; i < 4; ++i) {
            int k = kg + b_k + i * 4;
            float v = (k < 256) ? Ws[(size_t)k * N + n0 + b_n]
                                : Wn[(size_t)(k - 256) * N + n0 + b_n];
            Bs[b_k + i * 4][b_n] = v;
        }
        __syncthreads();

        #pragma unroll
        for (int k = 0; k < 16; ++k) {
            float4 a4 = *(const float4*)&As[k][ty * 4];
            float4 b4 = *(const float4*)&Bs[k][tx * 4];
            acc[0][0] += a4.x * b4.x; acc[0][1] += a4.x * b4.y; acc[0][2] += a4.x * b4.z; acc[0][3] += a4.x * b4.w;
            acc[1][0] += a4.y * b4.x; acc[1][1] += a4.y * b4.y; acc[1][2] += a4.y * b4.z; acc[1][3] += a4.y * b4.w;
            acc[2][0] += a4.z * b4.x; acc[2][1] += a4.z * b4.y; acc[2][2] += a4.z * b4.z; acc[2][3] += a4.z * b4.w;
            acc[3][0] += a4.w * b4.x; acc[3][1] += a4.w * b4.y; acc[3][2] += a4.w * b4.z; acc[3][3] += a4.w * b4.w;
        }
        __syncthreads();
    }

    #pragma unroll
    for (int i = 0; i < 4; ++i) {
        int r = row0 + ty * 4 + i;
        if (r >= M) continue;
        #pragma unroll
        for (int j = 0; j < 4; ++j) {
            int n = n0 + tx * 4 + j;
            float v = acc[i][j] + bias[n];
            if (relu) v = fmaxf(v, 0.f);
            out[(size_t)r * N + n] = v;
        }
    }
}

extern "C" void kernel_launch(void* const* d_in, const int* in_sizes, int n_in,
                              void* d_out, int out_size, void* d_ws, size_t ws_size,
                              hipStream_t stream) {
    const float* x   = (const float*)d_in[0];
    const int*   src = (const int*)d_in[1];
    const int*   dst = (const int*)d_in[2];
    const float* Ws1 = (const float*)d_in[3];
    const float* Wn1 = (const float*)d_in[4];
    const float* b1  = (const float*)d_in[5];
    const float* Ws2 = (const float*)d_in[6];
    const float* Wn2 = (const float*)d_in[7];
    const float* b2  = (const float*)d_in[8];
    const float* Ws3 = (const float*)d_in[9];
    const float* Wn3 = (const float*)d_in[10];
    const float* b3  = (const float*)d_in[11];

    // workspace layout: agg | hA | hB (floats), then deg_i | cursor | nbr (ints)
    float* agg = (float*)d_ws;
    float* hA  = agg + (size_t)NN * DH;
    float* hB  = hA  + (size_t)NN * DH;
    int* deg_i  = (int*)(hB + (size_t)NN * DH);
    int* cursor = deg_i + 102400;
    int* nbr    = cursor + 102400;

    // ---- CSR build (once per launch; graph shared by all layers) ----
    hipMemsetAsync(deg_i, 0, NN * sizeof(int), stream);
    degi_kernel<<<(NE + 255) / 256, 256, 0, stream>>>(dst, deg_i);
    scan_kernel<<<1, 1024, 0, stream>>>(deg_i, cursor);
    scatter_kernel<<<(NE + 255) / 256, 256, 0, stream>>>(src, dst, cursor, nbr);
    // now cursor[d] = end offset; bucket d = nbr[end-deg .. end)

    const dim3 gemmGrid((NN + 63) / 64, 4);
    const dim3 gemmGrid3((NN + 63) / 64, 1);
    const int gatherBlocks = NN / 4;

    // layer 1
    gather_kernel<<<gatherBlocks, 256, 0, stream>>>(x, nbr, cursor, deg_i, agg);
    sage_gemm<<<gemmGrid, 256, 0, stream>>>(x, agg, Ws1, Wn1, b1, hA, NN, 256, 1);

    // layer 2
    gather_kernel<<<gatherBlocks, 256, 0, stream>>>(hA, nbr, cursor, deg_i, agg);
    sage_gemm<<<gemmGrid, 256, 0, stream>>>(hA, agg, Ws2, Wn2, b2, hB, NN, 256, 1);

    // layer 3 (no relu, N=64)
    gather_kernel<<<gatherBlocks, 256, 0, stream>>>(hB, nbr, cursor, deg_i, agg);
    sage_gemm<<<gemmGrid3, 256, 0, stream>>>(hB, agg, Ws3, Wn3, b3, (float*)d_out, NN, 64, 0);
}

// Round 3
// 864.069 us; speedup vs baseline: 10.7178x; 1.9241x over previous
//
#include <hip/hip_runtime.h>

// GraphSAGE 3-layer inference — R3: bf16 MFMA GEMM + bf16 CSR pull-gather.
// Layer: out = [h | mean_agg] (K=512, bf16) @ [Ws; Wn]^T-prepped (bf16) + b [+ReLU]
// Activations live in H[MPAD][512] bf16: cols 0..255 = h, 256..511 = agg.

#define NN 100000
#define NE 800000
#define MPAD 100096   // 782 * 128, so GEMM tiles never read OOB

typedef __attribute__((ext_vector_type(8))) short short8;
typedef __attribute__((ext_vector_type(4))) float floatx4;

__device__ __forceinline__ float bf2f(unsigned short u) {
    unsigned int x = ((unsigned int)u) << 16;
    return __builtin_bit_cast(float, x);
}
__device__ __forceinline__ unsigned short f2bf(float f) {
    unsigned int x = __builtin_bit_cast(unsigned int, f);
    x += 0x7fffu + ((x >> 16) & 1u);   // round-to-nearest-even
    return (unsigned short)(x >> 16);
}

// ---------------- CSR build ----------------
__global__ void degi_kernel(const int* __restrict__ dst, int* __restrict__ deg) {
    int e = blockIdx.x * blockDim.x + threadIdx.x;
    if (e < NE) atomicAdd(&deg[dst[e]], 1);
}

__global__ __launch_bounds__(1024) void scan_kernel(const int* __restrict__ deg,
                                                    int* __restrict__ cursor) {
    __shared__ int wsum[16];
    __shared__ int carry_s;
    const int tid = threadIdx.x, lane = tid & 63, w = tid >> 6;
    if (tid == 0) carry_s = 0;
    __syncthreads();
    for (int base = 0; base < NN; base += 1024) {
        int i = base + tid;
        int v = (i < NN) ? deg[i] : 0;
        int s = v;
        #pragma unroll
        for (int off = 1; off < 64; off <<= 1) {
            int t = __shfl_up(s, off, 64);
            if (lane >= off) s += t;
        }
        if (lane == 63) wsum[w] = s;
        __syncthreads();
        if (w == 0) {
            int ws_ = (lane < 16) ? wsum[lane] : 0;
            int t2 = ws_;
            #pragma unroll
            for (int off = 1; off < 16; off <<= 1) {
                int t = __shfl_up(t2, off, 64);
                if (lane >= off) t2 += t;
            }
            if (lane < 16) wsum[lane] = t2 - ws_;
        }
        __syncthreads();
        int excl = carry_s + wsum[w] + (s - v);
        if (i < NN) cursor[i] = excl;
        __syncthreads();
        if (tid == 1023) carry_s = excl + v;
        __syncthreads();
    }
}

__global__ void scatter_kernel(const int* __restrict__ src, const int* __restrict__ dst,
                               int* __restrict__ cursor, int* __restrict__ nbr) {
    int e = blockIdx.x * blockDim.x + threadIdx.x;
    if (e < NE) {
        int pos = atomicAdd(&cursor[dst[e]], 1);
        nbr[pos] = src[e];
    }
}

// ---------------- casts / weight prep ----------------
__global__ void cast_x_kernel(const float4* __restrict__ x, unsigned short* __restrict__ H) {
    int gid = blockIdx.x * 256 + threadIdx.x;   // NN*64 float4 groups
    if (gid >= NN * 64) return;
    int row = gid >> 6, col = (gid & 63) * 4;
    float4 v = x[gid];
    ushort4 o;
    o.x = f2bf(v.x); o.y = f2bf(v.y); o.z = f2bf(v.z); o.w = f2bf(v.w);
    *(ushort4*)&H[(size_t)row * 512 + col] = o;
}

// Bt[n][k] = bf16( k<256 ? Ws[k][n] : Wn[k-256][n] ),  Bt row-major [N][512]
__global__ void wprep_kernel(const float* __restrict__ Ws, const float* __restrict__ Wn,
                             unsigned short* __restrict__ Bt, int N) {
    int idx = blockIdx.x * 256 + threadIdx.x;
    if (idx >= N * 512) return;
    int n = idx >> 9, k = idx & 511;
    float v = (k < 256) ? Ws[(size_t)k * N + n] : Wn[(size_t)(k - 256) * N + n];
    Bt[idx] = f2bf(v);
}

// ---------------- pull-mean gather (bf16) ----------------
// One wave per dst node; lane covers 4 of the 256 feats (ushort4 = 8B).
// Reads H left half (stride 512), writes H right half.
__global__ __launch_bounds__(256) void gather_bf16(unsigned short* __restrict__ H,
                                                   const int* __restrict__ nbr,
                                                   const int* __restrict__ cursor,
                                                   const int* __restrict__ deg) {
    const int lane = threadIdx.x & 63;
    const int sub  = threadIdx.x >> 6;
    const int d = blockIdx.x * 4 + sub;
    if (d >= NN) return;
    const int dg  = deg[d];
    const int end = cursor[d];
    float a0 = 0.f, a1 = 0.f, a2 = 0.f, a3 = 0.f;
    for (int j = end - dg; j < end; ++j) {
        int s = nbr[j];
        ushort4 v = *(const ushort4*)&H[(size_t)s * 512 + lane * 4];
        a0 += bf2f(v.x); a1 += bf2f(v.y); a2 += bf2f(v.z); a3 += bf2f(v.w);
    }
    const float inv = 1.0f / fmaxf((float)dg, 1.0f);
    ushort4 o;
    o.x = f2bf(a0 * inv); o.y = f2bf(a1 * inv); o.z = f2bf(a2 * inv); o.w = f2bf(a3 * inv);
    *(ushort4*)&H[(size_t)d * 512 + 256 + lane * 4] = o;
}

// ---------------- bf16 MFMA GEMM ----------------
// C[M, BNtot] = A[M,512] @ Bt^T + bias.  A rows stride 512 (bf16), Bt [BNtot][512].
// Block: 128 x (NFRAG*32) tile, 4 waves in 2x2, 16x16x32 mfma.
// LDS in fragment order: subtile (16 rows x 32 k) = 64 lanes x 16B, staged with
// global_load_lds width=16 using the exact per-lane fragment source permutation,
// so both staging and ds_read_b128 are conflict-free with zero VALU repack.
template <int NFRAG, bool OUTBF>
__global__ __launch_bounds__(256) void sage_mfma(const unsigned short* __restrict__ A,
                                                 const unsigned short* __restrict__ Bt,
                                                 const float* __restrict__ bias,
                                                 void* __restrict__ Cout, int ldc) {
    constexpr int NB = NFRAG * 2;            // B subtiles per k-tile
    __shared__ unsigned short smem[(8 + NB) * 512];
    unsigned short* smA = smem;
    unsigned short* smB = smem + 8 * 512;

    const int tid  = threadIdx.x;
    const int lane = tid & 63;
    const int w    = tid >> 6;
    const int wm   = w >> 1, wn = w & 1;
    const int m0   = blockIdx.x * 128;
    const int n0   = blockIdx.y * (NFRAG * 32);
    const int lr   = lane & 15;              // fragment m (A) / n (B) index
    const int lq   = lane >> 4;              // k-quad

    floatx4 acc[4][NFRAG] = {};

    for (int kt = 0; kt < 16; ++kt) {
        const int k0 = kt * 32;
        for (int idx = w; idx < 8 + NB; idx += 4) {
            const unsigned short* g;
            unsigned short* l;
            if (idx < 8) {
                g = A  + (size_t)(m0 + idx * 16 + lr) * 512 + k0 + lq * 8;
                l = smA + idx * 512;
            } else {
                int nt = idx - 8;
                g = Bt + (size_t)(n0 + nt * 16 + lr) * 512 + k0 + lq * 8;
                l = smB + nt * 512;
            }
            __builtin_amdgcn_global_load_lds((const __attribute__((address_space(1))) void*)g,
                                             (__attribute__((address_space(3))) void*)l,
                                             16, 0, 0);
        }
        __syncthreads();

        short8 af[4], bfv[NFRAG];
        #pragma unroll
        for (int mi = 0; mi < 4; ++mi)
            af[mi] = *(const short8*)&smA[(wm * 4 + mi) * 512 + lane * 8];
        #pragma unroll
        for (int ni = 0; ni < NFRAG; ++ni)
            bfv[ni] = *(const short8*)&smB[(wn * NFRAG + ni) * 512 + lane * 8];
        #pragma unroll
        for (int mi = 0; mi < 4; ++mi)
            #pragma unroll
            for (int ni = 0; ni < NFRAG; ++ni)
                acc[mi][ni] = __builtin_amdgcn_mfma_f32_16x16x32_bf16(af[mi], bfv[ni],
                                                                      acc[mi][ni], 0, 0, 0);
        __syncthreads();
    }

    // Epilogue: D row = lq*4 + reg, col = lr (per 16x16 tile).
    #pragma unroll
    for (int ni = 0; ni < NFRAG; ++ni) {
        const int c  = n0 + wn * (NFRAG * 16) + ni * 16 + lr;
        const float bv = bias[c];
        #pragma unroll
        for (int mi = 0; mi < 4; ++mi) {
            const int rbase = m0 + wm * 64 + mi * 16 + lq * 4;
            #pragma unroll
            for (int r = 0; r < 4; ++r) {
                const int row = rbase + r;
                if (row < NN) {
                    float v = acc[mi][ni][r] + bv;
                    if (OUTBF) {
                        v = fmaxf(v, 0.f);
                        ((unsigned short*)Cout)[(size_t)row * ldc + c] = f2bf(v);
                    } else {
                        ((float*)Cout)[(size_t)row * ldc + c] = v;
                    }
                }
            }
        }
    }
}

extern "C" void kernel_launch(void* const* d_in, const int* in_sizes, int n_in,
                              void* d_out, int out_size, void* d_ws, size_t ws_size,
                              hipStream_t stream) {
    const float* x   = (const float*)d_in[0];
    const int*   src = (const int*)d_in[1];
    const int*   dst = (const int*)d_in[2];
    const float* Ws1 = (const float*)d_in[3];
    const float* Wn1 = (const float*)d_in[4];
    const float* b1  = (const float*)d_in[5];
    const float* Ws2 = (const float*)d_in[6];
    const float* Wn2 = (const float*)d_in[7];
    const float* b2  = (const float*)d_in[8];
    const float* Ws3 = (const float*)d_in[9];
    const float* Wn3 = (const float*)d_in[10];
    const float* b3  = (const float*)d_in[11];

    // workspace: H1 | H2 (bf16 [MPAD][512]) | Bt1 | Bt2 | Bt3 | deg | cursor | nbr
    unsigned short* H1  = (unsigned short*)d_ws;
    unsigned short* H2  = H1  + (size_t)MPAD * 512;
    unsigned short* Bt1 = H2  + (size_t)MPAD * 512;
    unsigned short* Bt2 = Bt1 + 256 * 512;
    unsigned short* Bt3 = Bt2 + 256 * 512;
    int* deg    = (int*)(Bt3 + 64 * 512);
    int* cursor = deg + 102400;
    int* nbr    = cursor + 102400;

    // CSR build (graph shared by all layers)
    hipMemsetAsync(deg, 0, NN * sizeof(int), stream);
    degi_kernel<<<(NE + 255) / 256, 256, 0, stream>>>(dst, deg);
    scan_kernel<<<1, 1024, 0, stream>>>(deg, cursor);
    scatter_kernel<<<(NE + 255) / 256, 256, 0, stream>>>(src, dst, cursor, nbr);
    // cursor[d] = end offset; bucket d = nbr[end-deg .. end)

    // bf16 prep
    cast_x_kernel<<<(NN * 64 + 255) / 256, 256, 0, stream>>>((const float4*)x, H1);
    wprep_kernel<<<512, 256, 0, stream>>>(Ws1, Wn1, Bt1, 256);
    wprep_kernel<<<512, 256, 0, stream>>>(Ws2, Wn2, Bt2, 256);
    wprep_kernel<<<128, 256, 0, stream>>>(Ws3, Wn3, Bt3, 64);

    const int gatherBlocks = (NN + 3) / 4;
    const dim3 g2(MPAD / 128, 2), g1(MPAD / 128, 1);

    // layer 1: H1 -> H2(left)
    gather_bf16<<<gatherBlocks, 256, 0, stream>>>(H1, nbr, cursor, deg);
    sage_mfma<4, true><<<g2, 256, 0, stream>>>(H1, Bt1, b1, H2, 512);

    // layer 2: H2 -> H1(left)
    gather_bf16<<<gatherBlocks, 256, 0, stream>>>(H2, nbr, cursor, deg);
    sage_mfma<4, true><<<g2, 256, 0, stream>>>(H2, Bt2, b2, H1, 512);

    // layer 3: H1 -> d_out (fp32, N=64, no relu)
    gather_bf16<<<gatherBlocks, 256, 0, stream>>>(H1, nbr, cursor, deg);
    sage_mfma<2, false><<<g1, 256, 0, stream>>>(H1, Bt3, b3, d_out, 64);
}

// Round 4
// 758.381 us; speedup vs baseline: 12.2114x; 1.1394x over previous
//
#include <hip/hip_runtime.h>

// GraphSAGE 3-layer inference — R4.
//  * GEMM: barrier-free, LDS-free K-loop (direct global fragment loads,
//    register double-buffer), operands swapped so lanes own 4 consecutive
//    output cols; C routed through LDS slab for coalesced 16B stores.
//  * Layer 3: post-projection aggregation (agg(H@Wn3) == agg(H)@Wn3),
//    K=256 GEMM -> T[.,128] = [H@Ws3+b3 | H@Wn3], then 64-wide gather+add.
//  * Gather: half-wave per edge (2 edges in flight), shfl_xor combine.
//  * Scan: int4, 25 iterations.

#define NN 100000
#define NE 800000
#define MPAD 100096   // 782 * 128

typedef __attribute__((ext_vector_type(8))) short short8;
typedef __attribute__((ext_vector_type(4))) float floatx4;

__device__ __forceinline__ float bf2f(unsigned short u) {
    unsigned int x = ((unsigned int)u) << 16;
    return __builtin_bit_cast(float, x);
}
__device__ __forceinline__ unsigned short f2bf(float f) {
    unsigned int x = __builtin_bit_cast(unsigned int, f);
    x += 0x7fffu + ((x >> 16) & 1u);   // round-to-nearest-even
    return (unsigned short)(x >> 16);
}

// ---------------- CSR build ----------------
__global__ void degi_kernel(const int* __restrict__ dst, int* __restrict__ deg) {
    int e = blockIdx.x * blockDim.x + threadIdx.x;
    if (e < NE) atomicAdd(&deg[dst[e]], 1);
}

// Exclusive scan of 102400 ints (int4 per thread, 25 iterations).
__global__ __launch_bounds__(1024) void scan_kernel(const int4* __restrict__ deg4,
                                                    int4* __restrict__ cur4) {
    __shared__ int wsum[16];
    __shared__ int carry_s;
    const int tid = threadIdx.x, lane = tid & 63, w = tid >> 6;
    if (tid == 0) carry_s = 0;
    __syncthreads();
    for (int base = 0; base < 25600; base += 1024) {
        int i = base + tid;
        int4 v = deg4[i];
        int t = v.x + v.y + v.z + v.w;
        int s = t;
        #pragma unroll
        for (int off = 1; off < 64; off <<= 1) {
            int u = __shfl_up(s, off, 64);
            if (lane >= off) s += u;
        }
        if (lane == 63) wsum[w] = s;
        __syncthreads();
        if (w == 0) {
            int ws_ = (lane < 16) ? wsum[lane] : 0;
            int t2 = ws_;
            #pragma unroll
            for (int off = 1; off < 16; off <<= 1) {
                int u = __shfl_up(t2, off, 64);
                if (lane >= off) t2 += u;
            }
            if (lane < 16) wsum[lane] = t2 - ws_;
        }
        __syncthreads();
        int excl = carry_s + wsum[w] + (s - t);
        int4 o;
        o.x = excl; o.y = o.x + v.x; o.z = o.y + v.y; o.w = o.z + v.z;
        cur4[i] = o;
        __syncthreads();
        if (tid == 1023) carry_s = excl + t;
        __syncthreads();
    }
}

__global__ void scatter_kernel(const int* __restrict__ src, const int* __restrict__ dst,
                               int* __restrict__ cursor, int* __restrict__ nbr) {
    int e = blockIdx.x * blockDim.x + threadIdx.x;
    if (e < NE) {
        int pos = atomicAdd(&cursor[dst[e]], 1);
        nbr[pos] = src[e];
    }
}

// ---------------- casts / weight prep ----------------
__global__ void cast_x_kernel(const float4* __restrict__ x, unsigned short* __restrict__ H) {
    int gid = blockIdx.x * 256 + threadIdx.x;   // NN*64 float4 groups
    if (gid >= NN * 64) return;
    int row = gid >> 6, col = (gid & 63) * 4;
    float4 v = x[gid];
    ushort4 o;
    o.x = f2bf(v.x); o.y = f2bf(v.y); o.z = f2bf(v.z); o.w = f2bf(v.w);
    *(ushort4*)&H[(size_t)row * 512 + col] = o;
}

// Bt[n][k] = bf16( k<256 ? Ws[k][n] : Wn[k-256][n] ),  [256][512]
__global__ void wprep_kernel(const float* __restrict__ Ws, const float* __restrict__ Wn,
                             unsigned short* __restrict__ Bt) {
    int idx = blockIdx.x * 256 + threadIdx.x;
    if (idx >= 256 * 512) return;
    int n = idx >> 9, k = idx & 511;
    float v = (k < 256) ? Ws[(size_t)k * 256 + n] : Wn[(size_t)(k - 256) * 256 + n];
    Bt[idx] = f2bf(v);
}

// Bt3[n][k] (n<128, k<256): n<64 -> Ws3[k][n], else Wn3[k][n-64]; b3ext = [b3 | 0]
__global__ void wprep3_kernel(const float* __restrict__ Ws3, const float* __restrict__ Wn3,
                              const float* __restrict__ b3, unsigned short* __restrict__ Bt3,
                              float* __restrict__ b3ext) {
    int idx = blockIdx.x * 256 + threadIdx.x;
    if (idx < 128 * 256) {
        int n = idx >> 8, k = idx & 255;
        float v = (n < 64) ? Ws3[(size_t)k * 64 + n] : Wn3[(size_t)k * 64 + (n - 64)];
        Bt3[idx] = f2bf(v);
    }
    if (idx < 128) b3ext[idx] = (idx < 64) ? b3[idx] : 0.f;
}

// ---------------- pull-mean gather (bf16, half-wave per edge) ----------------
__global__ __launch_bounds__(256) void gather_bf16(unsigned short* __restrict__ H,
                                                   const int* __restrict__ nbr,
                                                   const int* __restrict__ cursor,
                                                   const int* __restrict__ deg) {
    const int lane = threadIdx.x & 63;
    const int sub  = threadIdx.x >> 6;
    const int d = blockIdx.x * 4 + sub;
    if (d >= NN) return;
    const int dg = deg[d];
    const int end = cursor[d];
    const int start = end - dg;
    const int half = lane >> 5, l32 = lane & 31;
    float acc[8] = {0.f, 0.f, 0.f, 0.f, 0.f, 0.f, 0.f, 0.f};
    for (int j = start + half; j < end; j += 2) {
        int s = nbr[j];
        short8 v = *(const short8*)&H[(size_t)s * 512 + l32 * 8];
        #pragma unroll
        for (int i = 0; i < 8; ++i) acc[i] += bf2f((unsigned short)v[i]);
    }
    #pragma unroll
    for (int i = 0; i < 8; ++i) acc[i] += __shfl_xor(acc[i], 32, 64);
    if (half == 0) {
        const float inv = 1.0f / fmaxf((float)dg, 1.0f);
        short8 o;
        #pragma unroll
        for (int i = 0; i < 8; ++i) o[i] = (short)f2bf(acc[i] * inv);
        *(short8*)&H[(size_t)d * 512 + 256 + l32 * 8] = o;
    }
}

// ---------------- barrier-free bf16 MFMA GEMM ----------------
// C[128 x 128 per block] = A[.,KT*32] @ Bt^T + bias; A row stride 512 (H fmt),
// Bt row stride KT*32. Operands swapped: lane holds 4 consecutive out cols.
template <int KT, bool RELU>
__global__ __launch_bounds__(256) void sage_mfma(const unsigned short* __restrict__ A,
                                                 const unsigned short* __restrict__ Bt,
                                                 const float* __restrict__ bias,
                                                 unsigned short* __restrict__ Cout, int ldc) {
    __shared__ unsigned short slab[128 * 136];
    constexpr int BSTR = KT * 32;
    const int tid = threadIdx.x;
    const int lane = tid & 63;
    const int w = tid >> 6, wm = w >> 1, wn = w & 1;
    const int m0 = blockIdx.x * 128, n0 = blockIdx.y * 128;
    const int lr = lane & 15, lq = lane >> 4;

    const unsigned short* Ab = A  + (size_t)(m0 + wm * 64 + lr) * 512  + lq * 8;
    const unsigned short* Bb = Bt + (size_t)(n0 + wn * 64 + lr) * BSTR + lq * 8;

    floatx4 acc[4][4] = {};
    short8 a0[4], b0[4], a1[4], b1[4];

    auto load = [&](short8* a, short8* b, int kt) {
        #pragma unroll
        for (int mi = 0; mi < 4; ++mi) a[mi] = *(const short8*)(Ab + (size_t)mi * 16 * 512 + kt * 32);
        #pragma unroll
        for (int ni = 0; ni < 4; ++ni) b[ni] = *(const short8*)(Bb + (size_t)ni * 16 * BSTR + kt * 32);
    };
    auto compute = [&](short8* a, short8* b) {
        #pragma unroll
        for (int mi = 0; mi < 4; ++mi)
            #pragma unroll
            for (int ni = 0; ni < 4; ++ni)
                acc[mi][ni] = __builtin_amdgcn_mfma_f32_16x16x32_bf16(b[ni], a[mi],
                                                                      acc[mi][ni], 0, 0, 0);
    };

    load(a0, b0, 0);
    for (int kt = 0; kt < KT; kt += 2) {
        if (kt + 1 < KT) load(a1, b1, kt + 1);
        compute(a0, b0);
        if (kt + 2 < KT) load(a0, b0, kt + 2);
        if (kt + 1 < KT) compute(a1, b1);
    }

    // Epilogue: bias + (relu) + bf16 -> LDS slab -> coalesced 16B stores.
    #pragma unroll
    for (int mi = 0; mi < 4; ++mi) {
        const int rl = wm * 64 + mi * 16 + lr;
        #pragma unroll
        for (int ni = 0; ni < 4; ++ni) {
            const int cl = wn * 64 + ni * 16 + lq * 4;
            const float4 bv = *(const float4*)&bias[n0 + cl];
            float v0 = acc[mi][ni][0] + bv.x;
            float v1 = acc[mi][ni][1] + bv.y;
            float v2 = acc[mi][ni][2] + bv.z;
            float v3 = acc[mi][ni][3] + bv.w;
            if (RELU) {
                v0 = fmaxf(v0, 0.f); v1 = fmaxf(v1, 0.f);
                v2 = fmaxf(v2, 0.f); v3 = fmaxf(v3, 0.f);
            }
            ushort4 o;
            o.x = f2bf(v0); o.y = f2bf(v1); o.z = f2bf(v2); o.w = f2bf(v3);
            *(ushort4*)&slab[rl * 136 + cl] = o;
        }
    }
    __syncthreads();
    #pragma unroll
    for (int it = 0; it < 8; ++it) {
        int idx = it * 256 + tid;
        int row = idx >> 4, c8 = (idx & 15) * 8;
        if (m0 + row < NN) {
            short8 v = *(const short8*)&slab[row * 136 + c8];
            *(short8*)&Cout[(size_t)(m0 + row) * ldc + n0 + c8] = v;
        }
    }
}

// ---------------- layer-3 finalize: out = S + mean_agg(P) ----------------
// T[.,128] bf16: cols 0-63 = S (bias folded), cols 64-127 = P.
__global__ __launch_bounds__(256) void final_out(const unsigned short* __restrict__ T,
                                                 const int* __restrict__ nbr,
                                                 const int* __restrict__ cursor,
                                                 const int* __restrict__ deg,
                                                 float* __restrict__ out) {
    const int lane = threadIdx.x & 63;
    const int sub  = threadIdx.x >> 6;
    const int d = blockIdx.x * 4 + sub;
    if (d >= NN) return;
    const int dg = deg[d];
    const int end = cursor[d];
    float a = 0.f;
    for (int j = end - dg; j < end; ++j) {
        int s = nbr[j];
        a += bf2f(T[(size_t)s * 128 + 64 + lane]);
    }
    const float inv = 1.0f / fmaxf((float)dg, 1.0f);
    const float sv = bf2f(T[(size_t)d * 128 + lane]);
    out[(size_t)d * 64 + lane] = sv + a * inv;
}

extern "C" void kernel_launch(void* const* d_in, const int* in_sizes, int n_in,
                              void* d_out, int out_size, void* d_ws, size_t ws_size,
                              hipStream_t stream) {
    const float* x   = (const float*)d_in[0];
    const int*   src = (const int*)d_in[1];
    const int*   dst = (const int*)d_in[2];
    const float* Ws1 = (const float*)d_in[3];
    const float* Wn1 = (const float*)d_in[4];
    const float* b1  = (const float*)d_in[5];
    const float* Ws2 = (const float*)d_in[6];
    const float* Wn2 = (const float*)d_in[7];
    const float* b2  = (const float*)d_in[8];
    const float* Ws3 = (const float*)d_in[9];
    const float* Wn3 = (const float*)d_in[10];
    const float* b3  = (const float*)d_in[11];

    unsigned short* H1  = (unsigned short*)d_ws;
    unsigned short* H2  = H1  + (size_t)MPAD * 512;
    unsigned short* T   = H2  + (size_t)MPAD * 512;
    unsigned short* Bt1 = T   + (size_t)MPAD * 128;
    unsigned short* Bt2 = Bt1 + 256 * 512;
    unsigned short* Bt3 = Bt2 + 256 * 512;
    float* b3ext = (float*)(Bt3 + 128 * 256);
    int* deg    = (int*)(b3ext + 128);
    int* cursor = deg + 102400;
    int* nbr    = cursor + 102400;

    // CSR build (graph shared by all layers); pad region zeroed for int4 scan.
    hipMemsetAsync(deg, 0, 102400 * sizeof(int), stream);
    degi_kernel<<<(NE + 255) / 256, 256, 0, stream>>>(dst, deg);
    scan_kernel<<<1, 1024, 0, stream>>>((const int4*)deg, (int4*)cursor);
    scatter_kernel<<<(NE + 255) / 256, 256, 0, stream>>>(src, dst, cursor, nbr);
    // cursor[d] = end offset; bucket d = nbr[end-deg .. end)

    // bf16 prep
    cast_x_kernel<<<(NN * 64 + 255) / 256, 256, 0, stream>>>((const float4*)x, H1);
    wprep_kernel<<<512, 256, 0, stream>>>(Ws1, Wn1, Bt1);
    wprep_kernel<<<512, 256, 0, stream>>>(Ws2, Wn2, Bt2);
    wprep3_kernel<<<128, 256, 0, stream>>>(Ws3, Wn3, b3, Bt3, b3ext);

    const int gatherBlocks = (NN + 3) / 4;
    const dim3 g2(MPAD / 128, 2), g1(MPAD / 128, 1);

    // layer 1: H1 -> H2(left)
    gather_bf16<<<gatherBlocks, 256, 0, stream>>>(H1, nbr, cursor, deg);
    sage_mfma<16, true><<<g2, 256, 0, stream>>>(H1, Bt1, b1, H2, 512);

    // layer 2: H2 -> H1(left)
    gather_bf16<<<gatherBlocks, 256, 0, stream>>>(H2, nbr, cursor, deg);
    sage_mfma<16, true><<<g2, 256, 0, stream>>>(H2, Bt2, b2, H1, 512);

    // layer 3: T = [H1@Ws3+b3 | H1@Wn3] (K=256), then out = S + agg(P)
    sage_mfma<8, false><<<g1, 256, 0, stream>>>(H1, Bt3, b3ext, T, 128);
    final_out<<<gatherBlocks, 256, 0, stream>>>(T, nbr, cursor, deg, (float*)d_out);
}

// Round 5
// 754.756 us; speedup vs baseline: 12.2701x; 1.0048x over previous
//
#include <hip/hip_runtime.h>

// GraphSAGE 3-layer inference — R5.
//  * GEMM: barrier-free K-loop with DEPTH-4 register prefetch ring (distance 3)
//    for both A and B — 24 loads in flight per wave to hide ~900-cyc cold-HBM
//    latency. __launch_bounds__(256,2) budgets ~220 unified VGPRs.
//  * Gather / final_out: 2-way unrolled inner loop (2 row-reads in flight).
//  * Layer 3 stays post-projection: T = [H@Ws3+b3 | H@Wn3], out = S + agg(P).

#define NN 100000
#define NE 800000
#define MPAD 100096   // 782 * 128

typedef __attribute__((ext_vector_type(8))) short short8;
typedef __attribute__((ext_vector_type(4))) float floatx4;

__device__ __forceinline__ float bf2f(unsigned short u) {
    unsigned int x = ((unsigned int)u) << 16;
    return __builtin_bit_cast(float, x);
}
__device__ __forceinline__ unsigned short f2bf(float f) {
    unsigned int x = __builtin_bit_cast(unsigned int, f);
    x += 0x7fffu + ((x >> 16) & 1u);   // round-to-nearest-even
    return (unsigned short)(x >> 16);
}

// ---------------- CSR build ----------------
__global__ void degi_kernel(const int* __restrict__ dst, int* __restrict__ deg) {
    int e = blockIdx.x * blockDim.x + threadIdx.x;
    if (e < NE) atomicAdd(&deg[dst[e]], 1);
}

// Exclusive scan of 102400 ints (int4 per thread, 25 iterations).
__global__ __launch_bounds__(1024) void scan_kernel(const int4* __restrict__ deg4,
                                                    int4* __restrict__ cur4) {
    __shared__ int wsum[16];
    __shared__ int carry_s;
    const int tid = threadIdx.x, lane = tid & 63, w = tid >> 6;
    if (tid == 0) carry_s = 0;
    __syncthreads();
    for (int base = 0; base < 25600; base += 1024) {
        int i = base + tid;
        int4 v = deg4[i];
        int t = v.x + v.y + v.z + v.w;
        int s = t;
        #pragma unroll
        for (int off = 1; off < 64; off <<= 1) {
            int u = __shfl_up(s, off, 64);
            if (lane >= off) s += u;
        }
        if (lane == 63) wsum[w] = s;
        __syncthreads();
        if (w == 0) {
            int ws_ = (lane < 16) ? wsum[lane] : 0;
            int t2 = ws_;
            #pragma unroll
            for (int off = 1; off < 16; off <<= 1) {
                int u = __shfl_up(t2, off, 64);
                if (lane >= off) t2 += u;
            }
            if (lane < 16) wsum[lane] = t2 - ws_;
        }
        __syncthreads();
        int excl = carry_s + wsum[w] + (s - t);
        int4 o;
        o.x = excl; o.y = o.x + v.x; o.z = o.y + v.y; o.w = o.z + v.z;
        cur4[i] = o;
        __syncthreads();
        if (tid == 1023) carry_s = excl + t;
        __syncthreads();
    }
}

__global__ void scatter_kernel(const int* __restrict__ src, const int* __restrict__ dst,
                               int* __restrict__ cursor, int* __restrict__ nbr) {
    int e = blockIdx.x * blockDim.x + threadIdx.x;
    if (e < NE) {
        int pos = atomicAdd(&cursor[dst[e]], 1);
        nbr[pos] = src[e];
    }
}

// ---------------- casts / weight prep ----------------
__global__ void cast_x_kernel(const float4* __restrict__ x, unsigned short* __restrict__ H) {
    int gid = blockIdx.x * 256 + threadIdx.x;   // NN*64 float4 groups
    if (gid >= NN * 64) return;
    int row = gid >> 6, col = (gid & 63) * 4;
    float4 v = x[gid];
    ushort4 o;
    o.x = f2bf(v.x); o.y = f2bf(v.y); o.z = f2bf(v.z); o.w = f2bf(v.w);
    *(ushort4*)&H[(size_t)row * 512 + col] = o;
}

// Bt[n][k] = bf16( k<256 ? Ws[k][n] : Wn[k-256][n] ),  [256][512]
__global__ void wprep_kernel(const float* __restrict__ Ws, const float* __restrict__ Wn,
                             unsigned short* __restrict__ Bt) {
    int idx = blockIdx.x * 256 + threadIdx.x;
    if (idx >= 256 * 512) return;
    int n = idx >> 9, k = idx & 511;
    float v = (k < 256) ? Ws[(size_t)k * 256 + n] : Wn[(size_t)(k - 256) * 256 + n];
    Bt[idx] = f2bf(v);
}

// Bt3[n][k] (n<128, k<256): n<64 -> Ws3[k][n], else Wn3[k][n-64]; b3ext = [b3 | 0]
__global__ void wprep3_kernel(const float* __restrict__ Ws3, const float* __restrict__ Wn3,
                              const float* __restrict__ b3, unsigned short* __restrict__ Bt3,
                              float* __restrict__ b3ext) {
    int idx = blockIdx.x * 256 + threadIdx.x;
    if (idx < 128 * 256) {
        int n = idx >> 8, k = idx & 255;
        float v = (n < 64) ? Ws3[(size_t)k * 64 + n] : Wn3[(size_t)k * 64 + (n - 64)];
        Bt3[idx] = f2bf(v);
    }
    if (idx < 128) b3ext[idx] = (idx < 64) ? b3[idx] : 0.f;
}

// ---------------- pull-mean gather (bf16, half-wave per edge, 2x unroll) ----------------
__global__ __launch_bounds__(256) void gather_bf16(unsigned short* __restrict__ H,
                                                   const int* __restrict__ nbr,
                                                   const int* __restrict__ cursor,
                                                   const int* __restrict__ deg) {
    const int lane = threadIdx.x & 63;
    const int sub  = threadIdx.x >> 6;
    const int d = blockIdx.x * 4 + sub;
    if (d >= NN) return;
    const int dg = deg[d];
    const int end = cursor[d];
    const int start = end - dg;
    const int half = lane >> 5, l32 = lane & 31;
    float acc0[8] = {0.f, 0.f, 0.f, 0.f, 0.f, 0.f, 0.f, 0.f};
    float acc1[8] = {0.f, 0.f, 0.f, 0.f, 0.f, 0.f, 0.f, 0.f};
    int j = start + half;
    for (; j + 2 < end; j += 4) {
        int s0 = nbr[j], s1 = nbr[j + 2];
        short8 v0 = *(const short8*)&H[(size_t)s0 * 512 + l32 * 8];
        short8 v1 = *(const short8*)&H[(size_t)s1 * 512 + l32 * 8];
        #pragma unroll
        for (int i = 0; i < 8; ++i) acc0[i] += bf2f((unsigned short)v0[i]);
        #pragma unroll
        for (int i = 0; i < 8; ++i) acc1[i] += bf2f((unsigned short)v1[i]);
    }
    for (; j < end; j += 2) {
        int s0 = nbr[j];
        short8 v0 = *(const short8*)&H[(size_t)s0 * 512 + l32 * 8];
        #pragma unroll
        for (int i = 0; i < 8; ++i) acc0[i] += bf2f((unsigned short)v0[i]);
    }
    #pragma unroll
    for (int i = 0; i < 8; ++i) acc0[i] += acc1[i];
    #pragma unroll
    for (int i = 0; i < 8; ++i) acc0[i] += __shfl_xor(acc0[i], 32, 64);
    if (half == 0) {
        const float inv = 1.0f / fmaxf((float)dg, 1.0f);
        short8 o;
        #pragma unroll
        for (int i = 0; i < 8; ++i) o[i] = (short)f2bf(acc0[i] * inv);
        *(short8*)&H[(size_t)d * 512 + 256 + l32 * 8] = o;
    }
}

// ---------------- barrier-free bf16 MFMA GEMM, depth-4 prefetch ring ----------------
// C[128 x 128 per block] = A[.,KT*32] @ Bt^T + bias; A row stride 512 (H fmt),
// Bt row stride KT*32. Operands swapped in mfma: lane owns 4 consecutive cols.
template <int KT, bool RELU>
__global__ __launch_bounds__(256, 2) void sage_mfma(const unsigned short* __restrict__ A,
                                                    const unsigned short* __restrict__ Bt,
                                                    const float* __restrict__ bias,
                                                    unsigned short* __restrict__ Cout, int ldc) {
    __shared__ unsigned short slab[128 * 136];
    constexpr int BSTR = KT * 32;
    const int tid = threadIdx.x;
    const int lane = tid & 63;
    const int w = tid >> 6, wm = w >> 1, wn = w & 1;
    const int m0 = blockIdx.x * 128, n0 = blockIdx.y * 128;
    const int lr = lane & 15, lq = lane >> 4;

    const unsigned short* Ab = A  + (size_t)(m0 + wm * 64 + lr) * 512  + lq * 8;
    const unsigned short* Bb = Bt + (size_t)(n0 + wn * 64 + lr) * BSTR + lq * 8;

    floatx4 acc[4][4] = {};
    short8 abuf[4][4], bbuf[4][4];   // 4-deep rings, prefetch distance 3

    #pragma unroll
    for (int p = 0; p < 3; ++p) {
        #pragma unroll
        for (int mi = 0; mi < 4; ++mi)
            abuf[p][mi] = *(const short8*)(Ab + (size_t)mi * 16 * 512 + p * 32);
        #pragma unroll
        for (int ni = 0; ni < 4; ++ni)
            bbuf[p][ni] = *(const short8*)(Bb + (size_t)ni * 16 * BSTR + p * 32);
    }

    #pragma unroll
    for (int kt = 0; kt < KT; ++kt) {
        const int pf = kt + 3;
        if (pf < KT) {
            #pragma unroll
            for (int mi = 0; mi < 4; ++mi)
                abuf[pf & 3][mi] = *(const short8*)(Ab + (size_t)mi * 16 * 512 + pf * 32);
            #pragma unroll
            for (int ni = 0; ni < 4; ++ni)
                bbuf[pf & 3][ni] = *(const short8*)(Bb + (size_t)ni * 16 * BSTR + pf * 32);
        }
        #pragma unroll
        for (int mi = 0; mi < 4; ++mi)
            #pragma unroll
            for (int ni = 0; ni < 4; ++ni)
                acc[mi][ni] = __builtin_amdgcn_mfma_f32_16x16x32_bf16(bbuf[kt & 3][ni],
                                                                      abuf[kt & 3][mi],
                                                                      acc[mi][ni], 0, 0, 0);
    }

    // Epilogue: bias + (relu) + bf16 -> LDS slab -> coalesced 16B stores.
    #pragma unroll
    for (int mi = 0; mi < 4; ++mi) {
        const int rl = wm * 64 + mi * 16 + lr;
        #pragma unroll
        for (int ni = 0; ni < 4; ++ni) {
            const int cl = wn * 64 + ni * 16 + lq * 4;
            const float4 bv = *(const float4*)&bias[n0 + cl];
            float v0 = acc[mi][ni][0] + bv.x;
            float v1 = acc[mi][ni][1] + bv.y;
            float v2 = acc[mi][ni][2] + bv.z;
            float v3 = acc[mi][ni][3] + bv.w;
            if (RELU) {
                v0 = fmaxf(v0, 0.f); v1 = fmaxf(v1, 0.f);
                v2 = fmaxf(v2, 0.f); v3 = fmaxf(v3, 0.f);
            }
            ushort4 o;
            o.x = f2bf(v0); o.y = f2bf(v1); o.z = f2bf(v2); o.w = f2bf(v3);
            *(ushort4*)&slab[rl * 136 + cl] = o;
        }
    }
    __syncthreads();
    #pragma unroll
    for (int it = 0; it < 8; ++it) {
        int idx = it * 256 + tid;
        int row = idx >> 4, c8 = (idx & 15) * 8;
        if (m0 + row < NN) {
            short8 v = *(const short8*)&slab[row * 136 + c8];
            *(short8*)&Cout[(size_t)(m0 + row) * ldc + n0 + c8] = v;
        }
    }
}

// ---------------- layer-3 finalize: out = S + mean_agg(P), 2x unroll ----------------
__global__ __launch_bounds__(256) void final_out(const unsigned short* __restrict__ T,
                                                 const int* __restrict__ nbr,
                                                 const int* __restrict__ cursor,
                                                 const int* __restrict__ deg,
                                                 float* __restrict__ out) {
    const int lane = threadIdx.x & 63;
    const int sub  = threadIdx.x >> 6;
    const int d = blockIdx.x * 4 + sub;
    if (d >= NN) return;
    const int dg = deg[d];
    const int end = cursor[d];
    float a0 = 0.f, a1 = 0.f;
    int j = end - dg;
    for (; j + 1 < end; j += 2) {
        int s0 = nbr[j], s1 = nbr[j + 1];
        float u0 = bf2f(T[(size_t)s0 * 128 + 64 + lane]);
        float u1 = bf2f(T[(size_t)s1 * 128 + 64 + lane]);
        a0 += u0; a1 += u1;
    }
    if (j < end) a0 += bf2f(T[(size_t)nbr[j] * 128 + 64 + lane]);
    const float inv = 1.0f / fmaxf((float)dg, 1.0f);
    const float sv = bf2f(T[(size_t)d * 128 + lane]);
    out[(size_t)d * 64 + lane] = sv + (a0 + a1) * inv;
}

extern "C" void kernel_launch(void* const* d_in, const int* in_sizes, int n_in,
                              void* d_out, int out_size, void* d_ws, size_t ws_size,
                              hipStream_t stream) {
    const float* x   = (const float*)d_in[0];
    const int*   src = (const int*)d_in[1];
    const int*   dst = (const int*)d_in[2];
    const float* Ws1 = (const float*)d_in[3];
    const float* Wn1 = (const float*)d_in[4];
    const float* b1  = (const float*)d_in[5];
    const float* Ws2 = (const float*)d_in[6];
    const float* Wn2 = (const float*)d_in[7];
    const float* b2  = (const float*)d_in[8];
    const float* Ws3 = (const float*)d_in[9];
    const float* Wn3 = (const float*)d_in[10];
    const float* b3  = (const float*)d_in[11];

    unsigned short* H1  = (unsigned short*)d_ws;
    unsigned short* H2  = H1  + (size_t)MPAD * 512;
    unsigned short* T   = H2  + (size_t)MPAD * 512;
    unsigned short* Bt1 = T   + (size_t)MPAD * 128;
    unsigned short* Bt2 = Bt1 + 256 * 512;
    unsigned short* Bt3 = Bt2 + 256 * 512;
    float* b3ext = (float*)(Bt3 + 128 * 256);
    int* deg    = (int*)(b3ext + 128);
    int* cursor = deg + 102400;
    int* nbr    = cursor + 102400;

    // CSR build (graph shared by all layers); pad region zeroed for int4 scan.
    hipMemsetAsync(deg, 0, 102400 * sizeof(int), stream);
    degi_kernel<<<(NE + 255) / 256, 256, 0, stream>>>(dst, deg);
    scan_kernel<<<1, 1024, 0, stream>>>((const int4*)deg, (int4*)cursor);
    scatter_kernel<<<(NE + 255) / 256, 256, 0, stream>>>(src, dst, cursor, nbr);
    // cursor[d] = end offset; bucket d = nbr[end-deg .. end)

    // bf16 prep
    cast_x_kernel<<<(NN * 64 + 255) / 256, 256, 0, stream>>>((const float4*)x, H1);
    wprep_kernel<<<512, 256, 0, stream>>>(Ws1, Wn1, Bt1);
    wprep_kernel<<<512, 256, 0, stream>>>(Ws2, Wn2, Bt2);
    wprep3_kernel<<<128, 256, 0, stream>>>(Ws3, Wn3, b3, Bt3, b3ext);

    const int gatherBlocks = (NN + 3) / 4;
    const dim3 g2(MPAD / 128, 2), g1(MPAD / 128, 1);

    // layer 1: H1 -> H2(left)
    gather_bf16<<<gatherBlocks, 256, 0, stream>>>(H1, nbr, cursor, deg);
    sage_mfma<16, true><<<g2, 256, 0, stream>>>(H1, Bt1, b1, H2, 512);

    // layer 2: H2 -> H1(left)
    gather_bf16<<<gatherBlocks, 256, 0, stream>>>(H2, nbr, cursor, deg);
    sage_mfma<16, true><<<g2, 256, 0, stream>>>(H2, Bt2, b2, H1, 512);

    // layer 3: T = [H1@Ws3+b3 | H1@Wn3] (K=256), then out = S + agg(P)
    sage_mfma<8, false><<<g1, 256, 0, stream>>>(H1, Bt3, b3ext, T, 128);
    final_out<<<gatherBlocks, 256, 0, stream>>>(T, nbr, cursor, deg, (float*)d_out);
}